// Round 9
// baseline (155.678 us; speedup 1.0000x reference)
//
#include <hip/hip_runtime.h>
#include <cstdint>

#define DEV __device__ __forceinline__

typedef __bf16  bf16x8 __attribute__((ext_vector_type(8)));
typedef short   s16x8  __attribute__((ext_vector_type(8)));
typedef float   f32x4  __attribute__((ext_vector_type(4)));

#define QSCALE 0.18033688011112042f   /* 0.125 * log2(e) */
#define MOFF   17.312340490667560f    /* 12 * log2(e)    */

// fp32 -> bf16 round-to-nearest-even
DEV unsigned short f2bf(float f){
  union { float f; unsigned u; } v; v.f = f;
  unsigned r = v.u + 0x7fffu + ((v.u >> 16) & 1u);
  return (unsigned short)(r >> 16);
}

// pack two positive f32 -> 2 bf16 (round-half-up) in one dword: lo in low16
DEV unsigned pk2(float lo, float hi){
  unsigned a = __builtin_bit_cast(unsigned, lo) + 0x8000u;
  unsigned b = __builtin_bit_cast(unsigned, hi) + 0x8000u;
  return __builtin_amdgcn_perm(b, a, 0x07060302);  // {hi16(b),hi16(a)}
}

// async global->LDS, 16B per lane; LDS dest must be uniform_base + lane*16
DEV void gl2lds16(const void* g, void* l){
  __builtin_amdgcn_global_load_lds((__attribute__((address_space(1))) void*)(void*)(g),
                                   (__attribute__((address_space(3))) void*)(l), 16, 0, 0);
}

DEV f32x4 mfma16(bf16x8 a, bf16x8 b, f32x4 c){
  return __builtin_amdgcn_mfma_f32_16x16x32_bf16(a, b, c, 0, 0, 0);
}

// ---------------------------------------------------------------- prep (merged)
// blocks 0..1535: cast x; 1536: rel tables (*8); 1537..3264: transpose w_qkv;
// 3265..3840: transpose w_out
__global__ __launch_bounds__(256) void prep_kernel(const float* __restrict__ x,
                                                   short* __restrict__ xb,
                                                   const float* __restrict__ rph,
                                                   const float* __restrict__ rpw,
                                                   short* __restrict__ rphb,
                                                   short* __restrict__ rpwb,
                                                   const float* __restrict__ w_qkv,
                                                   short* __restrict__ wqT,
                                                   const float* __restrict__ w_out,
                                                   short* __restrict__ woT){
  __shared__ float tb[32][33];
  int b = blockIdx.x;
  if (b < 1536){
    int i = b * 256 + threadIdx.x;
    const float4* in4 = (const float4*)x;
    float4 f0 = in4[i*2], f1 = in4[i*2+1];
    s16x8 o;
    o[0]=(short)f2bf(f0.x); o[1]=(short)f2bf(f0.y); o[2]=(short)f2bf(f0.z); o[3]=(short)f2bf(f0.w);
    o[4]=(short)f2bf(f1.x); o[5]=(short)f2bf(f1.y); o[6]=(short)f2bf(f1.z); o[7]=(short)f2bf(f1.w);
    *(s16x8*)(xb + i*8) = o;
  } else if (b == 1536){
    int t = threadIdx.x;
    for (int j = 0; j < 16; j++){
      int idx = t*16 + j;
      if (idx < 4032){
        rphb[idx] = (short)f2bf(rph[idx] * 8.f);   // *8 compensates q pre-scale
        rpwb[idx] = (short)f2bf(rpw[idx] * 8.f);
      }
    }
  } else {
    const float* in; short* out; int R, C, bx, by;
    if (b < 3265){ int t = b - 1537; in = w_qkv; out = wqT; R = 768; C = 2304; bx = t % 72; by = t / 72; }
    else         { int t = b - 3265; in = w_out; out = woT; R = 768; C = 768;  bx = t % 24; by = t / 24; }
    int tx = threadIdx.x & 31, ty = threadIdx.x >> 5;
    int c0 = bx * 32, r0 = by * 32;
    for (int i = 0; i < 4; i++)
      tb[ty + i*8][tx] = in[(r0 + ty + i*8)*C + c0 + tx];
    __syncthreads();
    for (int i = 0; i < 4; i++)
      out[(c0 + ty + i*8)*R + r0 + tx] = (short)f2bf(tb[tx][ty + i*8]);
  }
}

// ---------------------------------------------------------------- QKV GEMM
// 128x96 tiles -> grid 32x24 = 768 blocks = exactly 3/CU (balanced).
// q stored PRE-SCALED by 0.125*log2e; q,k,v all (bh, n, d) coalesced.
__global__ __launch_bounds__(256) void qkv_gemm_kernel(const short* __restrict__ xb,
                                                       const short* __restrict__ wqT,
                                                       short* __restrict__ qb,
                                                       short* __restrict__ kb,
                                                       short* __restrict__ vb){
  __shared__ __align__(16) short As[128*64];
  __shared__ __align__(16) short Bs[96*64];
  const int tid = threadIdx.x, lane = tid & 63, wv = tid >> 6;
  const int quad = lane >> 4, mi = lane & 15;
  const int m0 = blockIdx.x * 128, n0 = blockIdx.y * 96;
  const int wrow = wv >> 1, wcol = wv & 1;
  const int srow = lane >> 3, scs = lane & 7;
  const int sc = scs ^ (srow & 7);
  f32x4 acc[4][3] = {};
  for (int k0 = 0; k0 < 768; k0 += 64){
    __syncthreads();
    for (int i = 0; i < 4; i++){
      int rbase = i*32 + wv*8;
      int row = rbase + srow;
      gl2lds16(xb + (m0+row)*768 + k0 + sc*8, As + rbase*64 + lane*8);
    }
    for (int i = 0; i < 3; i++){
      int rbase = i*32 + wv*8;
      int row = rbase + srow;
      gl2lds16(wqT + (n0+row)*768 + k0 + sc*8, Bs + rbase*64 + lane*8);
    }
    __syncthreads();
    bf16x8 a[2][4], b[2][3];
#pragma unroll
    for (int kk = 0; kk < 2; kk++){
      int ccs = ((quad + kk*4) ^ (mi & 7)) * 8;
      for (int mt = 0; mt < 4; mt++) a[kk][mt] = *(const bf16x8*)(As + (wrow*64 + mt*16 + mi)*64 + ccs);
      for (int nt = 0; nt < 3; nt++) b[kk][nt] = *(const bf16x8*)(Bs + (wcol*48 + nt*16 + mi)*64 + ccs);
    }
#pragma unroll
    for (int kk = 0; kk < 2; kk++)
      for (int mt = 0; mt < 4; mt++)
        for (int nt = 0; nt < 3; nt++)
          acc[mt][nt] = mfma16(a[kk][mt], b[kk][nt], acc[mt][nt]);
  }
  const int which = n0 / 768;                    // uniform per block (768%96==0)
  const float qs = (which == 0) ? QSCALE : 1.0f;
  for (int nt = 0; nt < 3; nt++){
    int j = n0 + wcol*48 + nt*16 + mi;
    int rem = j % 768;
    int head = rem >> 6, d = rem & 63;
    short* dst = (which == 0) ? qb : (which == 1) ? kb : vb;
    for (int mt = 0; mt < 4; mt++)
      for (int r = 0; r < 4; r++){
        int m = m0 + wrow*64 + mt*16 + quad*4 + r;
        int bh = (m >> 10)*12 + head;
        dst[((bh << 10) + (m & 1023))*64 + d] = (short)f2bf(acc[mt][nt][r] * qs);
      }
  }
}

// ---------------------------------------------------------------- rel bias + v transpose (merged)
// relHT[bh][kh][n] = rel_h*log2e - 12*log2e  (TRANSPOSED so flash can stage
// it [kh][qrow] -> conflict-free per-step reads). relW[bh][n][kw] = rel_w*log2e.
// blocks 0..1535: rel; 1536..2303: vtrans
__global__ __launch_bounds__(256) void relvt_kernel(const short* __restrict__ qb,
                                                    const short* __restrict__ rphb,
                                                    const short* __restrict__ rpwb,
                                                    float* __restrict__ relHT,
                                                    float* __restrict__ relW,
                                                    const short* __restrict__ vb,
                                                    short* __restrict__ vtb){
  __shared__ __align__(16) short T[64*64];
  if (blockIdx.x < 1536){
    int wv = threadIdx.x >> 6, lane = threadIdx.x & 63;
    int bid = blockIdx.x*4 + wv;
    int quad = lane >> 4, mi = lane & 15;
    f32x4 acc[2] = {};
    if (bid < 3072){
      int bh = bid >> 6, rest = bid & 63, h = rest >> 1, half = rest & 1;
      const short* qr = qb + (bh*1024 + h*32 + half*16 + mi)*64;
      bf16x8 a0 = *(const bf16x8*)(qr + quad*8);
      bf16x8 a1 = *(const bf16x8*)(qr + 32 + quad*8);
      for (int nt = 0; nt < 2; nt++){
        int kh = nt*16 + mi;
        const short* rr = rphb + (h - kh + 31)*64;
        bf16x8 b0 = *(const bf16x8*)(rr + quad*8);
        bf16x8 b1 = *(const bf16x8*)(rr + 32 + quad*8);
        acc[nt] = mfma16(a0, b0, acc[nt]);
        acc[nt] = mfma16(a1, b1, acc[nt]);
      }
      // transposed write: relHT[bh*32768 + kh*1024 + h*32 + w], w=half*16+quad*4+r
      for (int nt = 0; nt < 2; nt++){
        f32x4 o;
        for (int r = 0; r < 4; r++) o[r] = acc[nt][r] - MOFF;
        *(f32x4*)&relHT[bh*32768 + (nt*16 + mi)*1024 + h*32 + half*16 + quad*4] = o;
      }
    } else {
      int bid2 = bid - 3072, w = bid2 / 96, rt = bid2 % 96;
      int rg = rt*16 + mi, bh = rg >> 5, h = rg & 31;
      const short* qr = qb + (bh*1024 + h*32 + w)*64;
      bf16x8 a0 = *(const bf16x8*)(qr + quad*8);
      bf16x8 a1 = *(const bf16x8*)(qr + 32 + quad*8);
      for (int nt = 0; nt < 2; nt++){
        int kw = nt*16 + mi;
        const short* rr = rpwb + (w - kw + 31)*64;
        bf16x8 b0 = *(const bf16x8*)(rr + quad*8);
        bf16x8 b1 = *(const bf16x8*)(rr + 32 + quad*8);
        acc[nt] = mfma16(a0, b0, acc[nt]);
        acc[nt] = mfma16(a1, b1, acc[nt]);
      }
      for (int nt = 0; nt < 2; nt++)
        for (int r = 0; r < 4; r++){
          int rowg = rt*16 + quad*4 + r;
          relW[(rowg*32 + w)*32 + nt*16 + mi] = acc[nt][r];
        }
    }
  } else {
    int blk = blockIdx.x - 1536;
    int t = threadIdx.x;
    int bh = blk >> 4, t0 = (blk & 15) * 64;
    const short* src = vb + (bh*1024 + t0)*64;
    for (int p = 0; p < 2; p++){
      int row = p*32 + (t >> 3);
      int c = (t & 7) ^ (row & 7);
      gl2lds16(src + row*64 + c*8, T + p*2048 + t*8);
    }
    __syncthreads();
    int d = t >> 2, k4 = t & 3;
    short vals[16];
    for (int j = 0; j < 16; j++){
      int k = k4 + j*4;
      int cs = (d >> 3) ^ (k & 7);
      vals[j] = T[k*64 + cs*8 + (d & 7)];
    }
    short* dst = vtb + (bh*64 + d)*1024 + t0;
    for (int j = 0; j < 16; j++)
      dst[k4 + j*4] = vals[j];
  }
}

// ---------------------------------------------------------------- flash attention
// Paired-step skeleton: stage K0,V0,K1,V1 (static buffers, no alternation,
// no conditionals) -> barrier -> compute 2 sub-steps -> barrier. Halves the
// vmcnt-drain count vs R6 while keeping its proven stage/compute structure.
// Pt aliases Qt after register preload (R7-proven); rw read from global once
// (R7-proven). LDS = 8(Qt/Pt) + 32(K/V) + 8(rHs) = 48 KB -> 3 blocks/CU.
__global__ __launch_bounds__(256, 3) void flash_kernel(const short* __restrict__ qb,
                                                       const short* __restrict__ kb,
                                                       const short* __restrict__ vtb,
                                                       const float* __restrict__ relHT,
                                                       const float* __restrict__ relW,
                                                       short* __restrict__ ao){
  __shared__ __align__(16) short QtPt[64*64];  // Qt, then Pt
  __shared__ __align__(16) short K0[64*64];
  __shared__ __align__(16) short K1[64*64];
  __shared__ __align__(16) short V0[64*64];    // [d][key], swizzled
  __shared__ __align__(16) short V1[64*64];
  __shared__ __align__(16) float rHs[32*64];   // [kh][qrow]
  const int tid = threadIdx.x, lane = tid & 63, wv = tid >> 6;
  const int quad = lane >> 4, mi = lane & 15;
  const int bh = blockIdx.y, n0 = blockIdx.x * 64;
  const int sw0 = (quad ^ (mi & 7)) * 8;
  const int sw1 = ((quad + 4) ^ (mi & 7)) * 8;
  const int qrow = wv*16 + mi;
  const int srow = lane >> 3;

  const short* kg = kb  + bh*1024*64;
  const short* vg = vtb + bh*64*1024;

  {
    const short* qg  = qb    + (bh*1024 + n0)*64;
    const float* rhg = relHT + bh*32768 + n0;       // row kh, stride 1024
    for (int i = 0; i < 2; i++){
      int slab = wv*2 + i, rbase = slab*8;
      int row = rbase + srow;
      int c = (lane & 7) ^ (row & 7);
      gl2lds16(qg + row*64 + c*8, QtPt + rbase*64 + lane*8);
      int khrow = i*16 + wv*4 + (lane >> 4);        // dest = base + lane*16B
      gl2lds16(rhg + khrow*1024 + (lane & 15)*4, rHs + i*1024 + wv*256 + lane*4);
    }
  }
  __syncthreads();

  bf16x8 qf0 = *(const bf16x8*)(QtPt + qrow*64 + sw0);
  bf16x8 qf1 = *(const bf16x8*)(QtPt + qrow*64 + sw1);
  float rw[2][4];
  {
    const float* rwg = relW + (bh*1024 + n0 + qrow)*32;
#pragma unroll
    for (int s = 0; s < 2; s++){
      float4 v4 = *(const float4*)(rwg + s*16 + quad*4);
      rw[s][0]=v4.x; rw[s][1]=v4.y; rw[s][2]=v4.z; rw[s][3]=v4.w;
    }
  }
  short* Pt = QtPt;   // Qt dead after preload; Pt rows are wave-private

  f32x4 O[4] = {};
  float l_ = 0.f;

#pragma unroll 1
  for (int s = 0; s < 8; s++){
    {
      const short* kt = kg + (2*s)*4096;
      for (int i = 0; i < 2; i++){
        int slab = wv*2 + i, rbase = slab*8;
        int row = rbase + srow;
        int c = (lane & 7) ^ (row & 7);
        gl2lds16(kt + row*64 + c*8,        K0 + rbase*64 + lane*8);
        gl2lds16(kt + 4096 + row*64 + c*8, K1 + rbase*64 + lane*8);
        gl2lds16(vg + row*1024 + (2*s)*64 + c*8,      V0 + rbase*64 + lane*8);
        gl2lds16(vg + row*1024 + (2*s)*64 + 64 + c*8, V1 + rbase*64 + lane*8);
      }
    }
    __syncthreads();

    // two fully-static sub-steps between one barrier pair
    const short* Kc[2] = {K0, K1};
    const short* Vc[2] = {V0, V1};
#pragma unroll
    for (int st = 0; st < 2; st++){
      f32x4 S[4];
#pragma unroll
      for (int nt = 0; nt < 4; nt++){
        bf16x8 kf0 = *(const bf16x8*)(Kc[st] + (nt*16 + mi)*64 + sw0);
        bf16x8 kf1 = *(const bf16x8*)(Kc[st] + (nt*16 + mi)*64 + sw1);
        f32x4 c = {};
        c = mfma16(kf0, qf0, c);
        c = mfma16(kf1, qf1, c);
        S[nt] = c;   // lane: qrow fixed, key = nt*16 + quad*4 + r
      }
      float kh0 = rHs[(4*s + 2*st)*64 + qrow];
      float kh1 = rHs[(4*s + 2*st + 1)*64 + qrow];
#pragma unroll
      for (int nt = 0; nt < 4; nt++){
        float kh = (nt & 2) ? kh1 : kh0;
        for (int r = 0; r < 4; r++){
          float p = __builtin_amdgcn_exp2f(S[nt][r] + kh + rw[nt & 1][r]);
          S[nt][r] = p;
          l_ += p;
        }
      }
      // P -> LDS (wave-private rows; same-wave DS ordering, no barrier)
#pragma unroll
      for (int nt = 0; nt < 4; nt++){
        unsigned u0 = pk2(S[nt][0], S[nt][1]);
        unsigned u1 = pk2(S[nt][2], S[nt][3]);
        int chunk = (2*nt + (quad >> 1)) ^ (mi & 7);
        uint2 uu; uu.x = u0; uu.y = u1;
        *(uint2*)(Pt + qrow*64 + chunk*8 + (quad & 1)*4) = uu;
      }
      bf16x8 p0 = *(const bf16x8*)(Pt + qrow*64 + sw0);
      bf16x8 p1 = *(const bf16x8*)(Pt + qrow*64 + sw1);
#pragma unroll
      for (int t = 0; t < 4; t++){
        bf16x8 v0 = *(const bf16x8*)(Vc[st] + (t*16 + mi)*64 + sw0);
        bf16x8 v1 = *(const bf16x8*)(Vc[st] + (t*16 + mi)*64 + sw1);
        O[t] = mfma16(p0, v0, O[t]);
        O[t] = mfma16(p1, v1, O[t]);
      }
    }
    __syncthreads();   // all waves done with K*/V* before next stage
  }

  l_ += __shfl_xor(l_, 16, 64);
  l_ += __shfl_xor(l_, 32, 64);
  float inv[4];
#pragma unroll
  for (int r = 0; r < 4; r++) inv[r] = 1.f / __shfl(l_, quad*4 + r, 64);
  int b_ = bh / 12, head = bh % 12;
#pragma unroll
  for (int t = 0; t < 4; t++)
    for (int r = 0; r < 4; r++){
      int n = n0 + wv*16 + quad*4 + r;
      ao[(b_*1024 + n)*768 + head*64 + t*16 + mi] = (short)f2bf(O[t][r] * inv[r]);
    }
}

// ---------------------------------------------------------------- out proj (128x64 tiles, 384 blocks)
__global__ __launch_bounds__(256) void proj_kernel(const short* __restrict__ ao,
                                                   const short* __restrict__ woT,
                                                   const float* __restrict__ bias,
                                                   float* __restrict__ out){
  __shared__ __align__(16) short As[128*64];
  __shared__ __align__(16) short Bs[64*64];
  const int tid = threadIdx.x, lane = tid & 63, wv = tid >> 6;
  const int quad = lane >> 4, mi = lane & 15;
  const int m0 = blockIdx.x * 128, n0 = blockIdx.y * 64;
  const int srow = lane >> 3, sc = (lane & 7) ^ (srow & 7);
  f32x4 acc[2][4] = {};
  for (int k0 = 0; k0 < 768; k0 += 64){
    __syncthreads();
    for (int i = 0; i < 4; i++){
      int rbase = i*32 + wv*8, row = rbase + srow;
      gl2lds16(ao + (m0+row)*768 + k0 + sc*8, As + rbase*64 + lane*8);
    }
    for (int i = 0; i < 2; i++){
      int rbase = i*32 + wv*8, row = rbase + srow;
      gl2lds16(woT + (n0+row)*768 + k0 + sc*8, Bs + rbase*64 + lane*8);
    }
    __syncthreads();
#pragma unroll
    for (int kk = 0; kk < 2; kk++){
      int ccs = ((quad + kk*4) ^ (mi & 7)) * 8;
      bf16x8 a[2], b[4];
      for (int mt = 0; mt < 2; mt++) a[mt] = *(const bf16x8*)(As + (wv*32 + mt*16 + mi)*64 + ccs);
      for (int nt = 0; nt < 4; nt++) b[nt] = *(const bf16x8*)(Bs + (nt*16 + mi)*64 + ccs);
      for (int mt = 0; mt < 2; mt++)
        for (int nt = 0; nt < 4; nt++)
          acc[mt][nt] = mfma16(a[mt], b[nt], acc[mt][nt]);
    }
  }
  for (int nt = 0; nt < 4; nt++){
    int j = n0 + nt*16 + mi;
    float bj = bias[j];
    for (int mt = 0; mt < 2; mt++)
      for (int r = 0; r < 4; r++){
        int m = m0 + wv*32 + mt*16 + quad*4 + r;
        out[m*768 + j] = acc[mt][nt][r] + bj;
      }
  }
}

// ---------------------------------------------------------------- launch
extern "C" void kernel_launch(void* const* d_in, const int* in_sizes, int n_in,
                              void* d_out, int out_size, void* d_ws, size_t ws_size,
                              hipStream_t stream){
  const float* x     = (const float*)d_in[0];
  const float* w_qkv = (const float*)d_in[1];
  const float* w_out = (const float*)d_in[2];
  const float* b_out = (const float*)d_in[3];
  const float* rph   = (const float*)d_in[4];
  const float* rpw   = (const float*)d_in[5];
  float* out = (float*)d_out;
  char* ws = (char*)d_ws;
  short* xb    = (short*)(ws + 0);          // 4096x768 bf16 (reused as ao after qkv)
  short* wqT   = (short*)(ws + 6291456);    // 2304x768 bf16
  short* woT   = (short*)(ws + 9830400);    // 768x768 bf16
  short* qb    = (short*)(ws + 11010048);   // 48x1024x64 bf16 (pre-scaled 0.125*log2e)
  short* kb    = (short*)(ws + 17301504);   // 48x1024x64 bf16
  short* vb    = (short*)(ws + 23592960);   // 48x1024x64 bf16
  short* vtb   = (short*)(ws + 29884416);   // 48x64x1024 bf16
  float* relHT = (float*)(ws + 36175872);   // 48x32x1024 f32 (TRANSPOSED, -M folded)
  float* relW  = (float*)(ws + 42467328);   // 48x1024x32 f32 (log2e-scaled)
  short* rphb  = (short*)(ws + 48758784);   // 63x64 bf16 (*8)
  short* rpwb  = (short*)(ws + 48775168);   // 63x64 bf16 (*8)
  short* ao    = xb;                        // reuse

  prep_kernel<<<3841, 256, 0, stream>>>(x, xb, rph, rpw, rphb, rpwb, w_qkv, wqT, w_out, woT);
  qkv_gemm_kernel<<<dim3(32, 24), 256, 0, stream>>>(xb, wqT, qb, kb, vb);
  relvt_kernel<<<2304, 256, 0, stream>>>(qb, rphb, rpwb, relHT, relW, vb, vtb);
  flash_kernel<<<dim3(16, 48), 256, 0, stream>>>(qb, kb, vtb, relHT, relW, ao);
  proj_kernel<<<dim3(32, 12), 256, 0, stream>>>(ao, woT, b_out, out);
}

// Round 10
// 152.094 us; speedup vs baseline: 1.0236x; 1.0236x over previous
//
#include <hip/hip_runtime.h>
#include <cstdint>

#define DEV __device__ __forceinline__

typedef __bf16  bf16x8 __attribute__((ext_vector_type(8)));
typedef short   s16x8  __attribute__((ext_vector_type(8)));
typedef float   f32x4  __attribute__((ext_vector_type(4)));

#define QSCALE 0.18033688011112042f   /* 0.125 * log2(e) */
#define MOFF   17.312340490667560f    /* 12 * log2(e)    */

// fp32 -> bf16 round-to-nearest-even
DEV unsigned short f2bf(float f){
  union { float f; unsigned u; } v; v.f = f;
  unsigned r = v.u + 0x7fffu + ((v.u >> 16) & 1u);
  return (unsigned short)(r >> 16);
}

// pack two positive f32 -> 2 bf16 (round-half-up) in one dword: lo in low16
DEV unsigned pk2(float lo, float hi){
  unsigned a = __builtin_bit_cast(unsigned, lo) + 0x8000u;
  unsigned b = __builtin_bit_cast(unsigned, hi) + 0x8000u;
  return __builtin_amdgcn_perm(b, a, 0x07060302);  // {hi16(b),hi16(a)}
}

// async global->LDS, 16B per lane; LDS dest must be uniform_base + lane*16
DEV void gl2lds16(const void* g, void* l){
  __builtin_amdgcn_global_load_lds((__attribute__((address_space(1))) void*)(void*)(g),
                                   (__attribute__((address_space(3))) void*)(l), 16, 0, 0);
}

DEV f32x4 mfma16(bf16x8 a, bf16x8 b, f32x4 c){
  return __builtin_amdgcn_mfma_f32_16x16x32_bf16(a, b, c, 0, 0, 0);
}

// ---------------------------------------------------------------- prep (merged)
// blocks 0..1535: cast x; 1536: rel tables (*8); 1537..3264: transpose w_qkv;
// 3265..3840: transpose w_out
__global__ __launch_bounds__(256) void prep_kernel(const float* __restrict__ x,
                                                   short* __restrict__ xb,
                                                   const float* __restrict__ rph,
                                                   const float* __restrict__ rpw,
                                                   short* __restrict__ rphb,
                                                   short* __restrict__ rpwb,
                                                   const float* __restrict__ w_qkv,
                                                   short* __restrict__ wqT,
                                                   const float* __restrict__ w_out,
                                                   short* __restrict__ woT){
  __shared__ float tb[32][33];
  int b = blockIdx.x;
  if (b < 1536){
    int i = b * 256 + threadIdx.x;
    const float4* in4 = (const float4*)x;
    float4 f0 = in4[i*2], f1 = in4[i*2+1];
    s16x8 o;
    o[0]=(short)f2bf(f0.x); o[1]=(short)f2bf(f0.y); o[2]=(short)f2bf(f0.z); o[3]=(short)f2bf(f0.w);
    o[4]=(short)f2bf(f1.x); o[5]=(short)f2bf(f1.y); o[6]=(short)f2bf(f1.z); o[7]=(short)f2bf(f1.w);
    *(s16x8*)(xb + i*8) = o;
  } else if (b == 1536){
    int t = threadIdx.x;
    for (int j = 0; j < 16; j++){
      int idx = t*16 + j;
      if (idx < 4032){
        rphb[idx] = (short)f2bf(rph[idx] * 8.f);   // *8 compensates q pre-scale
        rpwb[idx] = (short)f2bf(rpw[idx] * 8.f);
      }
    }
  } else {
    const float* in; short* out; int R, C, bx, by;
    if (b < 3265){ int t = b - 1537; in = w_qkv; out = wqT; R = 768; C = 2304; bx = t % 72; by = t / 72; }
    else         { int t = b - 3265; in = w_out; out = woT; R = 768; C = 768;  bx = t % 24; by = t / 24; }
    int tx = threadIdx.x & 31, ty = threadIdx.x >> 5;
    int c0 = bx * 32, r0 = by * 32;
    for (int i = 0; i < 4; i++)
      tb[ty + i*8][tx] = in[(r0 + ty + i*8)*C + c0 + tx];
    __syncthreads();
    for (int i = 0; i < 4; i++)
      out[(c0 + ty + i*8)*R + r0 + tx] = (short)f2bf(tb[tx][ty + i*8]);
  }
}

// ---------------------------------------------------------------- QKV GEMM
// 128x96 tiles -> grid 32x24 = 768 blocks = exactly 3/CU (balanced).
// q stored PRE-SCALED by 0.125*log2e; q,k,v all (bh, n, d) coalesced.
__global__ __launch_bounds__(256) void qkv_gemm_kernel(const short* __restrict__ xb,
                                                       const short* __restrict__ wqT,
                                                       short* __restrict__ qb,
                                                       short* __restrict__ kb,
                                                       short* __restrict__ vb){
  __shared__ __align__(16) short As[128*64];
  __shared__ __align__(16) short Bs[96*64];
  const int tid = threadIdx.x, lane = tid & 63, wv = tid >> 6;
  const int quad = lane >> 4, mi = lane & 15;
  const int m0 = blockIdx.x * 128, n0 = blockIdx.y * 96;
  const int wrow = wv >> 1, wcol = wv & 1;
  const int srow = lane >> 3, scs = lane & 7;
  const int sc = scs ^ (srow & 7);
  f32x4 acc[4][3] = {};
  for (int k0 = 0; k0 < 768; k0 += 64){
    __syncthreads();
    for (int i = 0; i < 4; i++){
      int rbase = i*32 + wv*8;
      int row = rbase + srow;
      gl2lds16(xb + (m0+row)*768 + k0 + sc*8, As + rbase*64 + lane*8);
    }
    for (int i = 0; i < 3; i++){
      int rbase = i*32 + wv*8;
      int row = rbase + srow;
      gl2lds16(wqT + (n0+row)*768 + k0 + sc*8, Bs + rbase*64 + lane*8);
    }
    __syncthreads();
    bf16x8 a[2][4], b[2][3];
#pragma unroll
    for (int kk = 0; kk < 2; kk++){
      int ccs = ((quad + kk*4) ^ (mi & 7)) * 8;
      for (int mt = 0; mt < 4; mt++) a[kk][mt] = *(const bf16x8*)(As + (wrow*64 + mt*16 + mi)*64 + ccs);
      for (int nt = 0; nt < 3; nt++) b[kk][nt] = *(const bf16x8*)(Bs + (wcol*48 + nt*16 + mi)*64 + ccs);
    }
#pragma unroll
    for (int kk = 0; kk < 2; kk++)
      for (int mt = 0; mt < 4; mt++)
        for (int nt = 0; nt < 3; nt++)
          acc[mt][nt] = mfma16(a[kk][mt], b[kk][nt], acc[mt][nt]);
  }
  const int which = n0 / 768;                    // uniform per block (768%96==0)
  const float qs = (which == 0) ? QSCALE : 1.0f;
  for (int nt = 0; nt < 3; nt++){
    int j = n0 + wcol*48 + nt*16 + mi;
    int rem = j % 768;
    int head = rem >> 6, d = rem & 63;
    short* dst = (which == 0) ? qb : (which == 1) ? kb : vb;
    for (int mt = 0; mt < 4; mt++)
      for (int r = 0; r < 4; r++){
        int m = m0 + wrow*64 + mt*16 + quad*4 + r;
        int bh = (m >> 10)*12 + head;
        dst[((bh << 10) + (m & 1023))*64 + d] = (short)f2bf(acc[mt][nt][r] * qs);
      }
  }
}

// ---------------------------------------------------------------- rel bias + v transpose (merged)
// relHT[bh][kh][n] = rel_h*log2e - 12*log2e  (TRANSPOSED so flash can stage
// it [kh][qrow] -> conflict-free per-step reads). relW[bh][n][kw] = rel_w*log2e.
// blocks 0..1535: rel; 1536..2303: vtrans
__global__ __launch_bounds__(256) void relvt_kernel(const short* __restrict__ qb,
                                                    const short* __restrict__ rphb,
                                                    const short* __restrict__ rpwb,
                                                    float* __restrict__ relHT,
                                                    float* __restrict__ relW,
                                                    const short* __restrict__ vb,
                                                    short* __restrict__ vtb){
  __shared__ __align__(16) short T[64*64];
  if (blockIdx.x < 1536){
    int wv = threadIdx.x >> 6, lane = threadIdx.x & 63;
    int bid = blockIdx.x*4 + wv;
    int quad = lane >> 4, mi = lane & 15;
    f32x4 acc[2] = {};
    if (bid < 3072){
      int bh = bid >> 6, rest = bid & 63, h = rest >> 1, half = rest & 1;
      const short* qr = qb + (bh*1024 + h*32 + half*16 + mi)*64;
      bf16x8 a0 = *(const bf16x8*)(qr + quad*8);
      bf16x8 a1 = *(const bf16x8*)(qr + 32 + quad*8);
      for (int nt = 0; nt < 2; nt++){
        int kh = nt*16 + mi;
        const short* rr = rphb + (h - kh + 31)*64;
        bf16x8 b0 = *(const bf16x8*)(rr + quad*8);
        bf16x8 b1 = *(const bf16x8*)(rr + 32 + quad*8);
        acc[nt] = mfma16(a0, b0, acc[nt]);
        acc[nt] = mfma16(a1, b1, acc[nt]);
      }
      // transposed write: relHT[bh*32768 + kh*1024 + h*32 + w], w=half*16+quad*4+r
      for (int nt = 0; nt < 2; nt++){
        f32x4 o;
        for (int r = 0; r < 4; r++) o[r] = acc[nt][r] - MOFF;
        *(f32x4*)&relHT[bh*32768 + (nt*16 + mi)*1024 + h*32 + half*16 + quad*4] = o;
      }
    } else {
      int bid2 = bid - 3072, w = bid2 / 96, rt = bid2 % 96;
      int rg = rt*16 + mi, bh = rg >> 5, h = rg & 31;
      const short* qr = qb + (bh*1024 + h*32 + w)*64;
      bf16x8 a0 = *(const bf16x8*)(qr + quad*8);
      bf16x8 a1 = *(const bf16x8*)(qr + 32 + quad*8);
      for (int nt = 0; nt < 2; nt++){
        int kw = nt*16 + mi;
        const short* rr = rpwb + (w - kw + 31)*64;
        bf16x8 b0 = *(const bf16x8*)(rr + quad*8);
        bf16x8 b1 = *(const bf16x8*)(rr + 32 + quad*8);
        acc[nt] = mfma16(a0, b0, acc[nt]);
        acc[nt] = mfma16(a1, b1, acc[nt]);
      }
      for (int nt = 0; nt < 2; nt++)
        for (int r = 0; r < 4; r++){
          int rowg = rt*16 + quad*4 + r;
          relW[(rowg*32 + w)*32 + nt*16 + mi] = acc[nt][r];
        }
    }
  } else {
    int blk = blockIdx.x - 1536;
    int t = threadIdx.x;
    int bh = blk >> 4, t0 = (blk & 15) * 64;
    const short* src = vb + (bh*1024 + t0)*64;
    for (int p = 0; p < 2; p++){
      int row = p*32 + (t >> 3);
      int c = (t & 7) ^ (row & 7);
      gl2lds16(src + row*64 + c*8, T + p*2048 + t*8);
    }
    __syncthreads();
    int d = t >> 2, k4 = t & 3;
    short vals[16];
    for (int j = 0; j < 16; j++){
      int k = k4 + j*4;
      int cs = (d >> 3) ^ (k & 7);
      vals[j] = T[k*64 + cs*8 + (d & 7)];
    }
    short* dst = vtb + (bh*64 + d)*1024 + t0;
    for (int j = 0; j < 16; j++)
      dst[k4 + j*4] = vals[j];
  }
}

// ---------------------------------------------------------------- flash attention
// R8-champion structure (verbatim revert): single K/V buffer, stage -> barrier
// -> compute -> barrier. S^T layout; fixed-max softmax (M folded into relHT);
// exp2 folding; deferred l-reduction; rHs [kh][qrow] conflict-free.
// 768 blocks = 3/CU exactly. (R7 2-q-tile and R9 paired-step both regressed.)
__global__ __launch_bounds__(256, 3) void flash_kernel(const short* __restrict__ qb,
                                                       const short* __restrict__ kb,
                                                       const short* __restrict__ vtb,
                                                       const float* __restrict__ relHT,
                                                       const float* __restrict__ relW,
                                                       short* __restrict__ ao){
  __shared__ __align__(16) short Qt[64*64];
  __shared__ __align__(16) short Kt[64*64];
  __shared__ __align__(16) short Vt[64*64];   // [d][key], swizzled
  __shared__ __align__(16) short Pt[64*64];   // [qrow][key], swizzled
  __shared__ __align__(16) float rHs[32*64];  // [kh][qrow]
  __shared__ __align__(16) float rWs[64*32];  // [qrow][kw]
  const int tid = threadIdx.x, lane = tid & 63, wv = tid >> 6;
  const int quad = lane >> 4, mi = lane & 15;
  const int bh = blockIdx.y, n0 = blockIdx.x * 64;
  const int sw0 = (quad ^ (mi & 7)) * 8;
  const int sw1 = ((quad + 4) ^ (mi & 7)) * 8;
  const int qrow = wv*16 + mi;
  const int srow = lane >> 3;

  const short* kg = kb  + bh*1024*64;
  const short* vg = vtb + bh*64*1024;

  {
    const short* qg  = qb    + (bh*1024 + n0)*64;
    const float* rhg = relHT + bh*32768 + n0;       // row kh, stride 1024
    const float* rwg = relW  + (bh*1024 + n0)*32;
    for (int i = 0; i < 2; i++){
      int slab = wv*2 + i, rbase = slab*8;
      int row = rbase + srow;
      int c = (lane & 7) ^ (row & 7);
      gl2lds16(qg + row*64 + c*8, Qt + rbase*64 + lane*8);
      int khrow = i*16 + wv*4 + (lane >> 4);        // dest = base + lane*16B
      gl2lds16(rhg + khrow*1024 + (lane & 15)*4, rHs + i*1024 + wv*256 + lane*4);
      gl2lds16(rwg + slab*256 + lane*4, rWs + slab*256 + lane*4);
    }
  }
  __syncthreads();

  bf16x8 qf0 = *(const bf16x8*)(Qt + qrow*64 + sw0);
  bf16x8 qf1 = *(const bf16x8*)(Qt + qrow*64 + sw1);
  float rw[2][4];
#pragma unroll
  for (int s = 0; s < 2; s++)
    for (int r = 0; r < 4; r++)
      rw[s][r] = rWs[qrow*32 + s*16 + quad*4 + r];

  f32x4 O[4] = {};
  float l_ = 0.f;

  for (int step = 0; step < 16; step++){
    {
      const short* kt = kg + step*64*64;
      for (int i = 0; i < 2; i++){
        int slab = wv*2 + i, rbase = slab*8;
        int row = rbase + srow;
        int c = (lane & 7) ^ (row & 7);
        gl2lds16(kt + row*64 + c*8, Kt + rbase*64 + lane*8);
        gl2lds16(vg + row*1024 + step*64 + c*8, Vt + rbase*64 + lane*8);
      }
    }
    __syncthreads();

    // S^T: A = K-frag (rows=keys), B = Q-frag (cols=qrows)
    f32x4 S[4];
#pragma unroll
    for (int nt = 0; nt < 4; nt++){
      bf16x8 kf0 = *(const bf16x8*)(Kt + (nt*16 + mi)*64 + sw0);
      bf16x8 kf1 = *(const bf16x8*)(Kt + (nt*16 + mi)*64 + sw1);
      f32x4 c = {};
      c = mfma16(kf0, qf0, c);
      c = mfma16(kf1, qf1, c);
      S[nt] = c;   // lane: qrow fixed, key = nt*16 + quad*4 + r
    }
    // p = exp2(S + kh' + rw')  (M folded into kh'); conflict-free [kh][qrow] reads
    float kh0 = rHs[(2*step)*64 + qrow];
    float kh1 = rHs[(2*step + 1)*64 + qrow];
#pragma unroll
    for (int nt = 0; nt < 4; nt++){
      float kh = (nt & 2) ? kh1 : kh0;
      for (int r = 0; r < 4; r++){
        float p = __builtin_amdgcn_exp2f(S[nt][r] + kh + rw[nt & 1][r]);
        S[nt][r] = p;
        l_ += p;
      }
    }
    // P -> LDS: row qrow, cols nt*16+quad*4+{0..3}: 4x ds_write_b64, swizzled
#pragma unroll
    for (int nt = 0; nt < 4; nt++){
      unsigned u0 = pk2(S[nt][0], S[nt][1]);
      unsigned u1 = pk2(S[nt][2], S[nt][3]);
      int chunk = (2*nt + (quad >> 1)) ^ (mi & 7);
      uint2 uu; uu.x = u0; uu.y = u1;
      *(uint2*)(Pt + qrow*64 + chunk*8 + (quad & 1)*4) = uu;
    }
    // PV (wave-private Pt rows: same-wave DS ordering, no barrier needed)
    bf16x8 p0 = *(const bf16x8*)(Pt + qrow*64 + sw0);
    bf16x8 p1 = *(const bf16x8*)(Pt + qrow*64 + sw1);
#pragma unroll
    for (int t = 0; t < 4; t++){
      bf16x8 v0 = *(const bf16x8*)(Vt + (t*16 + mi)*64 + sw0);
      bf16x8 v1 = *(const bf16x8*)(Vt + (t*16 + mi)*64 + sw1);
      O[t] = mfma16(p0, v0, O[t]);
      O[t] = mfma16(p1, v1, O[t]);
    }
    __syncthreads();   // all waves done with Kt/Vt before next stage
  }

  l_ += __shfl_xor(l_, 16, 64);
  l_ += __shfl_xor(l_, 32, 64);
  float inv[4];
#pragma unroll
  for (int r = 0; r < 4; r++) inv[r] = 1.f / __shfl(l_, quad*4 + r, 64);
  int b_ = bh / 12, head = bh % 12;
#pragma unroll
  for (int t = 0; t < 4; t++)
    for (int r = 0; r < 4; r++){
      int n = n0 + wv*16 + quad*4 + r;
      ao[(b_*1024 + n)*768 + head*64 + t*16 + mi] = (short)f2bf(O[t][r] * inv[r]);
    }
}

// ---------------------------------------------------------------- out proj
// 64x96 tiles -> grid 64x8 = 512 blocks = exactly 2/CU (was 384 = 1.5/CU).
// ao re-reads drop 12x -> 8x; woT (1.2 MB) is L2-resident either way.
__global__ __launch_bounds__(256) void proj_kernel(const short* __restrict__ ao,
                                                   const short* __restrict__ woT,
                                                   const float* __restrict__ bias,
                                                   float* __restrict__ out){
  __shared__ __align__(16) short As[64*64];
  __shared__ __align__(16) short Bs[96*64];
  const int tid = threadIdx.x, lane = tid & 63, wv = tid >> 6;
  const int quad = lane >> 4, mi = lane & 15;
  const int m0 = blockIdx.x * 64, n0 = blockIdx.y * 96;
  const int wrow = wv >> 1, wcol = wv & 1;         // wave tile: 32 rows x 48 cols
  const int srow = lane >> 3, sc = (lane & 7) ^ (srow & 7);
  f32x4 acc[2][3] = {};
  for (int k0 = 0; k0 < 768; k0 += 64){
    __syncthreads();
    for (int i = 0; i < 2; i++){
      int rbase = i*32 + wv*8, row = rbase + srow;
      gl2lds16(ao + (m0+row)*768 + k0 + sc*8, As + rbase*64 + lane*8);
    }
    for (int i = 0; i < 3; i++){
      int rbase = i*32 + wv*8, row = rbase + srow;
      gl2lds16(woT + (n0+row)*768 + k0 + sc*8, Bs + rbase*64 + lane*8);
    }
    __syncthreads();
    bf16x8 a[2][2], b[2][3];
#pragma unroll
    for (int kk = 0; kk < 2; kk++){
      int ccs = ((quad + kk*4) ^ (mi & 7)) * 8;
      for (int mt = 0; mt < 2; mt++) a[kk][mt] = *(const bf16x8*)(As + (wrow*32 + mt*16 + mi)*64 + ccs);
      for (int nt = 0; nt < 3; nt++) b[kk][nt] = *(const bf16x8*)(Bs + (wcol*48 + nt*16 + mi)*64 + ccs);
    }
#pragma unroll
    for (int kk = 0; kk < 2; kk++)
      for (int mt = 0; mt < 2; mt++)
        for (int nt = 0; nt < 3; nt++)
          acc[mt][nt] = mfma16(a[kk][mt], b[kk][nt], acc[mt][nt]);
  }
  for (int nt = 0; nt < 3; nt++){
    int j = n0 + wcol*48 + nt*16 + mi;
    float bj = bias[j];
    for (int mt = 0; mt < 2; mt++)
      for (int r = 0; r < 4; r++){
        int m = m0 + wrow*32 + mt*16 + quad*4 + r;
        out[m*768 + j] = acc[mt][nt][r] + bj;
      }
  }
}

// ---------------------------------------------------------------- launch
extern "C" void kernel_launch(void* const* d_in, const int* in_sizes, int n_in,
                              void* d_out, int out_size, void* d_ws, size_t ws_size,
                              hipStream_t stream){
  const float* x     = (const float*)d_in[0];
  const float* w_qkv = (const float*)d_in[1];
  const float* w_out = (const float*)d_in[2];
  const float* b_out = (const float*)d_in[3];
  const float* rph   = (const float*)d_in[4];
  const float* rpw   = (const float*)d_in[5];
  float* out = (float*)d_out;
  char* ws = (char*)d_ws;
  short* xb    = (short*)(ws + 0);          // 4096x768 bf16 (reused as ao after qkv)
  short* wqT   = (short*)(ws + 6291456);    // 2304x768 bf16
  short* woT   = (short*)(ws + 9830400);    // 768x768 bf16
  short* qb    = (short*)(ws + 11010048);   // 48x1024x64 bf16 (pre-scaled 0.125*log2e)
  short* kb    = (short*)(ws + 17301504);   // 48x1024x64 bf16
  short* vb    = (short*)(ws + 23592960);   // 48x1024x64 bf16
  short* vtb   = (short*)(ws + 29884416);   // 48x64x1024 bf16
  float* relHT = (float*)(ws + 36175872);   // 48x32x1024 f32 (TRANSPOSED, -M folded)
  float* relW  = (float*)(ws + 42467328);   // 48x1024x32 f32 (log2e-scaled)
  short* rphb  = (short*)(ws + 48758784);   // 63x64 bf16 (*8)
  short* rpwb  = (short*)(ws + 48775168);   // 63x64 bf16 (*8)
  short* ao    = xb;                        // reuse

  prep_kernel<<<3841, 256, 0, stream>>>(x, xb, rph, rpw, rphb, rpwb, w_qkv, wqT, w_out, woT);
  qkv_gemm_kernel<<<dim3(32, 24), 256, 0, stream>>>(xb, wqT, qb, kb, vb);
  relvt_kernel<<<2304, 256, 0, stream>>>(qb, rphb, rpwb, relHT, relW, vb, vtb);
  flash_kernel<<<dim3(16, 48), 256, 0, stream>>>(qb, kb, vtb, relHT, relW, ao);
  proj_kernel<<<dim3(64, 8), 256, 0, stream>>>(ao, woT, b_out, out);
}

// Round 12
// 151.366 us; speedup vs baseline: 1.0285x; 1.0048x over previous
//
#include <hip/hip_runtime.h>
#include <cstdint>

#define DEV __device__ __forceinline__

typedef __bf16  bf16x8 __attribute__((ext_vector_type(8)));
typedef short   s16x8  __attribute__((ext_vector_type(8)));
typedef float   f32x4  __attribute__((ext_vector_type(4)));

#define QSCALE 0.18033688011112042f   /* 0.125 * log2(e) */
#define MOFF   17.312340490667560f    /* 12 * log2(e)    */

// fp32 -> bf16 round-to-nearest-even
DEV unsigned short f2bf(float f){
  union { float f; unsigned u; } v; v.f = f;
  unsigned r = v.u + 0x7fffu + ((v.u >> 16) & 1u);
  return (unsigned short)(r >> 16);
}

// pack two positive f32 -> 2 bf16 (round-half-up) in one dword: lo in low16
DEV unsigned pk2(float lo, float hi){
  unsigned a = __builtin_bit_cast(unsigned, lo) + 0x8000u;
  unsigned b = __builtin_bit_cast(unsigned, hi) + 0x8000u;
  return __builtin_amdgcn_perm(b, a, 0x07060302);  // {hi16(b),hi16(a)}
}

// async global->LDS, 16B per lane; LDS dest must be uniform_base + lane*16
DEV void gl2lds16(const void* g, void* l){
  __builtin_amdgcn_global_load_lds((__attribute__((address_space(1))) void*)(void*)(g),
                                   (__attribute__((address_space(3))) void*)(l), 16, 0, 0);
}

DEV f32x4 mfma16(bf16x8 a, bf16x8 b, f32x4 c){
  return __builtin_amdgcn_mfma_f32_16x16x32_bf16(a, b, c, 0, 0, 0);
}

// ---------------------------------------------------------------- prep (merged)
// blocks 0..1535: cast x; 1536: rel tables (*8); 1537..3264: transpose w_qkv;
// 3265..3840: transpose w_out
__global__ __launch_bounds__(256) void prep_kernel(const float* __restrict__ x,
                                                   short* __restrict__ xb,
                                                   const float* __restrict__ rph,
                                                   const float* __restrict__ rpw,
                                                   short* __restrict__ rphb,
                                                   short* __restrict__ rpwb,
                                                   const float* __restrict__ w_qkv,
                                                   short* __restrict__ wqT,
                                                   const float* __restrict__ w_out,
                                                   short* __restrict__ woT){
  __shared__ float tb[32][33];
  int b = blockIdx.x;
  if (b < 1536){
    int i = b * 256 + threadIdx.x;
    const float4* in4 = (const float4*)x;
    float4 f0 = in4[i*2], f1 = in4[i*2+1];
    s16x8 o;
    o[0]=(short)f2bf(f0.x); o[1]=(short)f2bf(f0.y); o[2]=(short)f2bf(f0.z); o[3]=(short)f2bf(f0.w);
    o[4]=(short)f2bf(f1.x); o[5]=(short)f2bf(f1.y); o[6]=(short)f2bf(f1.z); o[7]=(short)f2bf(f1.w);
    *(s16x8*)(xb + i*8) = o;
  } else if (b == 1536){
    int t = threadIdx.x;
    for (int j = 0; j < 16; j++){
      int idx = t*16 + j;
      if (idx < 4032){
        rphb[idx] = (short)f2bf(rph[idx] * 8.f);   // *8 compensates q pre-scale
        rpwb[idx] = (short)f2bf(rpw[idx] * 8.f);
      }
    }
  } else {
    const float* in; short* out; int R, C, bx, by;
    if (b < 3265){ int t = b - 1537; in = w_qkv; out = wqT; R = 768; C = 2304; bx = t % 72; by = t / 72; }
    else         { int t = b - 3265; in = w_out; out = woT; R = 768; C = 768;  bx = t % 24; by = t / 24; }
    int tx = threadIdx.x & 31, ty = threadIdx.x >> 5;
    int c0 = bx * 32, r0 = by * 32;
    for (int i = 0; i < 4; i++)
      tb[ty + i*8][tx] = in[(r0 + ty + i*8)*C + c0 + tx];
    __syncthreads();
    for (int i = 0; i < 4; i++)
      out[(c0 + ty + i*8)*R + r0 + tx] = (short)f2bf(tb[tx][ty + i*8]);
  }
}

// ---------------------------------------------------------------- QKV GEMM
// 128x96 tiles -> grid 32x24 = 768 blocks = exactly 3/CU (balanced).
// q stored PRE-SCALED by 0.125*log2e; q,k,v all (bh, n, d) coalesced.
__global__ __launch_bounds__(256) void qkv_gemm_kernel(const short* __restrict__ xb,
                                                       const short* __restrict__ wqT,
                                                       short* __restrict__ qb,
                                                       short* __restrict__ kb,
                                                       short* __restrict__ vb){
  __shared__ __align__(16) short As[128*64];
  __shared__ __align__(16) short Bs[96*64];
  const int tid = threadIdx.x, lane = tid & 63, wv = tid >> 6;
  const int quad = lane >> 4, mi = lane & 15;
  const int m0 = blockIdx.x * 128, n0 = blockIdx.y * 96;
  const int wrow = wv >> 1, wcol = wv & 1;
  const int srow = lane >> 3, scs = lane & 7;
  const int sc = scs ^ (srow & 7);
  f32x4 acc[4][3] = {};
  for (int k0 = 0; k0 < 768; k0 += 64){
    __syncthreads();
    for (int i = 0; i < 4; i++){
      int rbase = i*32 + wv*8;
      int row = rbase + srow;
      gl2lds16(xb + (m0+row)*768 + k0 + sc*8, As + rbase*64 + lane*8);
    }
    for (int i = 0; i < 3; i++){
      int rbase = i*32 + wv*8;
      int row = rbase + srow;
      gl2lds16(wqT + (n0+row)*768 + k0 + sc*8, Bs + rbase*64 + lane*8);
    }
    __syncthreads();
    bf16x8 a[2][4], b[2][3];
#pragma unroll
    for (int kk = 0; kk < 2; kk++){
      int ccs = ((quad + kk*4) ^ (mi & 7)) * 8;
      for (int mt = 0; mt < 4; mt++) a[kk][mt] = *(const bf16x8*)(As + (wrow*64 + mt*16 + mi)*64 + ccs);
      for (int nt = 0; nt < 3; nt++) b[kk][nt] = *(const bf16x8*)(Bs + (wcol*48 + nt*16 + mi)*64 + ccs);
    }
#pragma unroll
    for (int kk = 0; kk < 2; kk++)
      for (int mt = 0; mt < 4; mt++)
        for (int nt = 0; nt < 3; nt++)
          acc[mt][nt] = mfma16(a[kk][mt], b[kk][nt], acc[mt][nt]);
  }
  const int which = n0 / 768;                    // uniform per block (768%96==0)
  const float qs = (which == 0) ? QSCALE : 1.0f;
  for (int nt = 0; nt < 3; nt++){
    int j = n0 + wcol*48 + nt*16 + mi;
    int rem = j % 768;
    int head = rem >> 6, d = rem & 63;
    short* dst = (which == 0) ? qb : (which == 1) ? kb : vb;
    for (int mt = 0; mt < 4; mt++)
      for (int r = 0; r < 4; r++){
        int m = m0 + wrow*64 + mt*16 + quad*4 + r;
        int bh = (m >> 10)*12 + head;
        dst[((bh << 10) + (m & 1023))*64 + d] = (short)f2bf(acc[mt][nt][r] * qs);
      }
  }
}

// ---------------------------------------------------------------- rel bias + v transpose (merged)
// relHT[bh][kh][n] = rel_h*log2e - 12*log2e  (TRANSPOSED so flash can stage
// it [kh][qrow] -> conflict-free per-step reads). relW[bh][n][kw] = rel_w*log2e.
// blocks 0..1535: rel; 1536..2303: vtrans
__global__ __launch_bounds__(256) void relvt_kernel(const short* __restrict__ qb,
                                                    const short* __restrict__ rphb,
                                                    const short* __restrict__ rpwb,
                                                    float* __restrict__ relHT,
                                                    float* __restrict__ relW,
                                                    const short* __restrict__ vb,
                                                    short* __restrict__ vtb){
  __shared__ __align__(16) short T[64*64];
  if (blockIdx.x < 1536){
    int wv = threadIdx.x >> 6, lane = threadIdx.x & 63;
    int bid = blockIdx.x*4 + wv;
    int quad = lane >> 4, mi = lane & 15;
    f32x4 acc[2] = {};
    if (bid < 3072){
      int bh = bid >> 6, rest = bid & 63, h = rest >> 1, half = rest & 1;
      const short* qr = qb + (bh*1024 + h*32 + half*16 + mi)*64;
      bf16x8 a0 = *(const bf16x8*)(qr + quad*8);
      bf16x8 a1 = *(const bf16x8*)(qr + 32 + quad*8);
      for (int nt = 0; nt < 2; nt++){
        int kh = nt*16 + mi;
        const short* rr = rphb + (h - kh + 31)*64;
        bf16x8 b0 = *(const bf16x8*)(rr + quad*8);
        bf16x8 b1 = *(const bf16x8*)(rr + 32 + quad*8);
        acc[nt] = mfma16(a0, b0, acc[nt]);
        acc[nt] = mfma16(a1, b1, acc[nt]);
      }
      // transposed write: relHT[bh*32768 + kh*1024 + h*32 + w], w=half*16+quad*4+r
      for (int nt = 0; nt < 2; nt++){
        f32x4 o;
        for (int r = 0; r < 4; r++) o[r] = acc[nt][r] - MOFF;
        *(f32x4*)&relHT[bh*32768 + (nt*16 + mi)*1024 + h*32 + half*16 + quad*4] = o;
      }
    } else {
      int bid2 = bid - 3072, w = bid2 / 96, rt = bid2 % 96;
      int rg = rt*16 + mi, bh = rg >> 5, h = rg & 31;
      const short* qr = qb + (bh*1024 + h*32 + w)*64;
      bf16x8 a0 = *(const bf16x8*)(qr + quad*8);
      bf16x8 a1 = *(const bf16x8*)(qr + 32 + quad*8);
      for (int nt = 0; nt < 2; nt++){
        int kw = nt*16 + mi;
        const short* rr = rpwb + (w - kw + 31)*64;
        bf16x8 b0 = *(const bf16x8*)(rr + quad*8);
        bf16x8 b1 = *(const bf16x8*)(rr + 32 + quad*8);
        acc[nt] = mfma16(a0, b0, acc[nt]);
        acc[nt] = mfma16(a1, b1, acc[nt]);
      }
      for (int nt = 0; nt < 2; nt++)
        for (int r = 0; r < 4; r++){
          int rowg = rt*16 + quad*4 + r;
          relW[(rowg*32 + w)*32 + nt*16 + mi] = acc[nt][r];
        }
    }
  } else {
    int blk = blockIdx.x - 1536;
    int t = threadIdx.x;
    int bh = blk >> 4, t0 = (blk & 15) * 64;
    const short* src = vb + (bh*1024 + t0)*64;
    for (int p = 0; p < 2; p++){
      int row = p*32 + (t >> 3);
      int c = (t & 7) ^ (row & 7);
      gl2lds16(src + row*64 + c*8, T + p*2048 + t*8);
    }
    __syncthreads();
    int d = t >> 2, k4 = t & 3;
    short vals[16];
    for (int j = 0; j < 16; j++){
      int k = k4 + j*4;
      int cs = (d >> 3) ^ (k & 7);
      vals[j] = T[k*64 + cs*8 + (d & 7)];
    }
    short* dst = vtb + (bh*64 + d)*1024 + t0;
    for (int j = 0; j < 16; j++)
      dst[k4 + j*4] = vals[j];
  }
}

// ---------------------------------------------------------------- flash attention
// R8-champion structure: single K/V buffer, stage -> barrier -> compute ->
// barrier. S^T layout; fixed-max softmax (M folded into relHT); exp2 folding;
// deferred l-reduction; rHs [kh][qrow] conflict-free. 768 blocks = 3/CU.
// (R7 2-q-tile, R9 paired-step, R11 overlap-staging all failed — this
// structure is the demonstrated local optimum.)
__global__ __launch_bounds__(256, 3) void flash_kernel(const short* __restrict__ qb,
                                                       const short* __restrict__ kb,
                                                       const short* __restrict__ vtb,
                                                       const float* __restrict__ relHT,
                                                       const float* __restrict__ relW,
                                                       short* __restrict__ ao){
  __shared__ __align__(16) short Qt[64*64];
  __shared__ __align__(16) short Kt[64*64];
  __shared__ __align__(16) short Vt[64*64];   // [d][key], swizzled
  __shared__ __align__(16) short Pt[64*64];   // [qrow][key], swizzled
  __shared__ __align__(16) float rHs[32*64];  // [kh][qrow]
  __shared__ __align__(16) float rWs[64*32];  // [qrow][kw]
  const int tid = threadIdx.x, lane = tid & 63, wv = tid >> 6;
  const int quad = lane >> 4, mi = lane & 15;
  const int bh = blockIdx.y, n0 = blockIdx.x * 64;
  const int sw0 = (quad ^ (mi & 7)) * 8;
  const int sw1 = ((quad + 4) ^ (mi & 7)) * 8;
  const int qrow = wv*16 + mi;
  const int srow = lane >> 3;

  const short* kg = kb  + bh*1024*64;
  const short* vg = vtb + bh*64*1024;

  {
    const short* qg  = qb    + (bh*1024 + n0)*64;
    const float* rhg = relHT + bh*32768 + n0;       // row kh, stride 1024
    const float* rwg = relW  + (bh*1024 + n0)*32;
    for (int i = 0; i < 2; i++){
      int slab = wv*2 + i, rbase = slab*8;
      int row = rbase + srow;
      int c = (lane & 7) ^ (row & 7);
      gl2lds16(qg + row*64 + c*8, Qt + rbase*64 + lane*8);
      int khrow = i*16 + wv*4 + (lane >> 4);        // dest = base + lane*16B
      gl2lds16(rhg + khrow*1024 + (lane & 15)*4, rHs + i*1024 + wv*256 + lane*4);
      gl2lds16(rwg + slab*256 + lane*4, rWs + slab*256 + lane*4);
    }
  }
  __syncthreads();

  bf16x8 qf0 = *(const bf16x8*)(Qt + qrow*64 + sw0);
  bf16x8 qf1 = *(const bf16x8*)(Qt + qrow*64 + sw1);
  float rw[2][4];
#pragma unroll
  for (int s = 0; s < 2; s++)
    for (int r = 0; r < 4; r++)
      rw[s][r] = rWs[qrow*32 + s*16 + quad*4 + r];

  f32x4 O[4] = {};
  float l_ = 0.f;

  for (int step = 0; step < 16; step++){
    {
      const short* kt = kg + step*64*64;
      for (int i = 0; i < 2; i++){
        int slab = wv*2 + i, rbase = slab*8;
        int row = rbase + srow;
        int c = (lane & 7) ^ (row & 7);
        gl2lds16(kt + row*64 + c*8, Kt + rbase*64 + lane*8);
        gl2lds16(vg + row*1024 + step*64 + c*8, Vt + rbase*64 + lane*8);
      }
    }
    __syncthreads();

    // S^T: A = K-frag (rows=keys), B = Q-frag (cols=qrows)
    f32x4 S[4];
#pragma unroll
    for (int nt = 0; nt < 4; nt++){
      bf16x8 kf0 = *(const bf16x8*)(Kt + (nt*16 + mi)*64 + sw0);
      bf16x8 kf1 = *(const bf16x8*)(Kt + (nt*16 + mi)*64 + sw1);
      f32x4 c = {};
      c = mfma16(kf0, qf0, c);
      c = mfma16(kf1, qf1, c);
      S[nt] = c;   // lane: qrow fixed, key = nt*16 + quad*4 + r
    }
    // p = exp2(S + kh' + rw')  (M folded into kh'); conflict-free [kh][qrow] reads
    float kh0 = rHs[(2*step)*64 + qrow];
    float kh1 = rHs[(2*step + 1)*64 + qrow];
#pragma unroll
    for (int nt = 0; nt < 4; nt++){
      float kh = (nt & 2) ? kh1 : kh0;
      for (int r = 0; r < 4; r++){
        float p = __builtin_amdgcn_exp2f(S[nt][r] + kh + rw[nt & 1][r]);
        S[nt][r] = p;
        l_ += p;
      }
    }
    // P -> LDS: row qrow, cols nt*16+quad*4+{0..3}: 4x ds_write_b64, swizzled
#pragma unroll
    for (int nt = 0; nt < 4; nt++){
      unsigned u0 = pk2(S[nt][0], S[nt][1]);
      unsigned u1 = pk2(S[nt][2], S[nt][3]);
      int chunk = (2*nt + (quad >> 1)) ^ (mi & 7);
      uint2 uu; uu.x = u0; uu.y = u1;
      *(uint2*)(Pt + qrow*64 + chunk*8 + (quad & 1)*4) = uu;
    }
    // PV (wave-private Pt rows: same-wave DS ordering, no barrier needed)
    bf16x8 p0 = *(const bf16x8*)(Pt + qrow*64 + sw0);
    bf16x8 p1 = *(const bf16x8*)(Pt + qrow*64 + sw1);
#pragma unroll
    for (int t = 0; t < 4; t++){
      bf16x8 v0 = *(const bf16x8*)(Vt + (t*16 + mi)*64 + sw0);
      bf16x8 v1 = *(const bf16x8*)(Vt + (t*16 + mi)*64 + sw1);
      O[t] = mfma16(p0, v0, O[t]);
      O[t] = mfma16(p1, v1, O[t]);
    }
    __syncthreads();   // all waves done with Kt/Vt before next stage
  }

  l_ += __shfl_xor(l_, 16, 64);
  l_ += __shfl_xor(l_, 32, 64);
  float inv[4];
#pragma unroll
  for (int r = 0; r < 4; r++) inv[r] = 1.f / __shfl(l_, quad*4 + r, 64);
  int b_ = bh / 12, head = bh % 12;
#pragma unroll
  for (int t = 0; t < 4; t++)
    for (int r = 0; r < 4; r++){
      int n = n0 + wv*16 + quad*4 + r;
      ao[(b_*1024 + n)*768 + head*64 + t*16 + mi] = (short)f2bf(O[t][r] * inv[r]);
    }
}

// ---------------------------------------------------------------- out proj
// 64x96 tiles -> grid 64x8 = 512 blocks = exactly 2/CU.
__global__ __launch_bounds__(256) void proj_kernel(const short* __restrict__ ao,
                                                   const short* __restrict__ woT,
                                                   const float* __restrict__ bias,
                                                   float* __restrict__ out){
  __shared__ __align__(16) short As[64*64];
  __shared__ __align__(16) short Bs[96*64];
  const int tid = threadIdx.x, lane = tid & 63, wv = tid >> 6;
  const int quad = lane >> 4, mi = lane & 15;
  const int m0 = blockIdx.x * 64, n0 = blockIdx.y * 96;
  const int wrow = wv >> 1, wcol = wv & 1;         // wave tile: 32 rows x 48 cols
  const int srow = lane >> 3, sc = (lane & 7) ^ (srow & 7);
  f32x4 acc[2][3] = {};
  for (int k0 = 0; k0 < 768; k0 += 64){
    __syncthreads();
    for (int i = 0; i < 2; i++){
      int rbase = i*32 + wv*8, row = rbase + srow;
      gl2lds16(ao + (m0+row)*768 + k0 + sc*8, As + rbase*64 + lane*8);
    }
    for (int i = 0; i < 3; i++){
      int rbase = i*32 + wv*8, row = rbase + srow;
      gl2lds16(woT + (n0+row)*768 + k0 + sc*8, Bs + rbase*64 + lane*8);
    }
    __syncthreads();
    bf16x8 a[2][2], b[2][3];
#pragma unroll
    for (int kk = 0; kk < 2; kk++){
      int ccs = ((quad + kk*4) ^ (mi & 7)) * 8;
      for (int mt = 0; mt < 2; mt++) a[kk][mt] = *(const bf16x8*)(As + (wrow*32 + mt*16 + mi)*64 + ccs);
      for (int nt = 0; nt < 3; nt++) b[kk][nt] = *(const bf16x8*)(Bs + (wcol*48 + nt*16 + mi)*64 + ccs);
    }
#pragma unroll
    for (int kk = 0; kk < 2; kk++)
      for (int mt = 0; mt < 2; mt++)
        for (int nt = 0; nt < 3; nt++)
          acc[mt][nt] = mfma16(a[kk][mt], b[kk][nt], acc[mt][nt]);
  }
  for (int nt = 0; nt < 3; nt++){
    int j = n0 + wcol*48 + nt*16 + mi;
    float bj = bias[j];
    for (int mt = 0; mt < 2; mt++)
      for (int r = 0; r < 4; r++){
        int m = m0 + wrow*32 + mt*16 + quad*4 + r;
        out[m*768 + j] = acc[mt][nt][r] + bj;
      }
  }
}

// ---------------------------------------------------------------- launch
extern "C" void kernel_launch(void* const* d_in, const int* in_sizes, int n_in,
                              void* d_out, int out_size, void* d_ws, size_t ws_size,
                              hipStream_t stream){
  const float* x     = (const float*)d_in[0];
  const float* w_qkv = (const float*)d_in[1];
  const float* w_out = (const float*)d_in[2];
  const float* b_out = (const float*)d_in[3];
  const float* rph   = (const float*)d_in[4];
  const float* rpw   = (const float*)d_in[5];
  float* out = (float*)d_out;
  char* ws = (char*)d_ws;
  short* xb    = (short*)(ws + 0);          // 4096x768 bf16 (reused as ao after qkv)
  short* wqT   = (short*)(ws + 6291456);    // 2304x768 bf16
  short* woT   = (short*)(ws + 9830400);    // 768x768 bf16
  short* qb    = (short*)(ws + 11010048);   // 48x1024x64 bf16 (pre-scaled 0.125*log2e)
  short* kb    = (short*)(ws + 17301504);   // 48x1024x64 bf16
  short* vb    = (short*)(ws + 23592960);   // 48x1024x64 bf16
  short* vtb   = (short*)(ws + 29884416);   // 48x64x1024 bf16
  float* relHT = (float*)(ws + 36175872);   // 48x32x1024 f32 (TRANSPOSED, -M folded)
  float* relW  = (float*)(ws + 42467328);   // 48x1024x32 f32 (log2e-scaled)
  short* rphb  = (short*)(ws + 48758784);   // 63x64 bf16 (*8)
  short* rpwb  = (short*)(ws + 48775168);   // 63x64 bf16 (*8)
  short* ao    = xb;                        // reuse

  prep_kernel<<<3841, 256, 0, stream>>>(x, xb, rph, rpw, rphb, rpwb, w_qkv, wqT, w_out, woT);
  qkv_gemm_kernel<<<dim3(32, 24), 256, 0, stream>>>(xb, wqT, qb, kb, vb);
  relvt_kernel<<<2304, 256, 0, stream>>>(qb, rphb, rpwb, relHT, relW, vb, vtb);
  flash_kernel<<<dim3(16, 48), 256, 0, stream>>>(qb, kb, vtb, relHT, relW, ao);
  proj_kernel<<<dim3(64, 8), 256, 0, stream>>>(ao, woT, b_out, out);
}